// Round 2
// baseline (246.308 us; speedup 1.0000x reference)
//
#include <hip/hip_runtime.h>
#include <math.h>

#define TT  34   // seq len
#define VV  14   // vocab
#define BLK 256  // threads per block
#define BCH 64   // b-rows per block
#define NCH 9    // t-chunks (4,4,4,4,4,4,4,4,2)
#define IDP 68   // idsb row pitch in bytes (64 + 4 pad: 17-word stride, conflict-free)

#if __has_builtin(__builtin_amdgcn_exp2f)
#define EXP2F(x) __builtin_amdgcn_exp2f(x)
#else
#define EXP2F(x) exp2f(x)
#endif

// wsm layout (floats):
//  0..35  out_w (6x6)      36..41 ln2_g   42..47 ln2_b
// 48..65  ffn_w1 (3x6)     66..68 ffn_b1
// 69..86  ffn_w2 (6x3)     87..92 ffn_b2
// 93..110 G[c][d]  = lnf_g[d]*head_w[c*6+d]   (folded LNF-scale x head)
// 111..113 sG[c]   = sum_d G[c][d]
// 114..116 eC[c]   = sum_d lnf_b[d]*head_w[c*6+d]
// 120..161 tok_emb (14x3)

__global__ __launch_bounds__(BLK) void addtx_fwd(
    const int*   __restrict__ idx,
    const float* __restrict__ tok_emb,
    const float* __restrict__ pos_enc,
    const float* __restrict__ q_w,
    const float* __restrict__ k_w,
    const float* __restrict__ v_w,
    const float* __restrict__ out_w,
    const float* __restrict__ ln1_g, const float* __restrict__ ln1_b,
    const float* __restrict__ ln2_g, const float* __restrict__ ln2_b,
    const float* __restrict__ lnf_g, const float* __restrict__ lnf_b,
    const float* __restrict__ ffn_w1, const float* __restrict__ ffn_b1,
    const float* __restrict__ ffn_w2, const float* __restrict__ ffn_b2,
    const float* __restrict__ head_w,
    float* __restrict__ out)
{
    // kv table: per (pos,tok): k0..3 | k4,k5,v0,v1 | v2..5  (k pre-scaled 1/sqrt(3)*log2e)
    // Reused as logits staging buffer after attention.
    __shared__ float4 kvs[TT * VV * 3];          // 22848 B
    __shared__ float  wsm[176];                  //   704 B
    __shared__ unsigned char idsb[35 * IDP];     //  2380 B  [s][bl] + prefetch row

    const int tid = threadIdx.x;

    // ---------------- XCD-grouped block decode ----------------
    // All 9 t-chunks of one b-chunk land on the same XCD (share idx tile in L2,
    // merge neighboring output segments in L2 before writeback).
    const int bx   = blockIdx.x;
    const int xcd  = bx & 7;
    const int jj   = bx >> 3;                    // 0 .. nbc8*NCH-1
    const int jd9  = jj / NCH;
    const int tc   = jj - jd9 * NCH;             // t-chunk 0..8
    const int nbc8 = (int)gridDim.x / (NCH * 8); // b-chunks per XCD
    const int bc   = xcd * nbc8 + jd9;
    const int b0   = bc * BCH;
    const int t_base = tc << 2;
    const int nt   = (tc == 8) ? 2 : 4;          // active waves (t values) this block
    const int nst  = t_base + nt + ((tc == 8) ? 0 : 0); // rows of kv needed = t_max+1
    const int nrow = (tc == 8) ? TT : (t_base + 4);     // = nst, explicit

    // ---------------- stage weights (folded epilogue forms) ----------------
    if (tid < 176) {
        float val = 0.0f;
        const int i = tid;
        if (i < 36)       val = out_w[i];
        else if (i < 42)  val = ln2_g[i - 36];
        else if (i < 48)  val = ln2_b[i - 42];
        else if (i < 66)  val = ffn_w1[i - 48];
        else if (i < 69)  val = ffn_b1[i - 66];
        else if (i < 87)  val = ffn_w2[i - 69];
        else if (i < 93)  val = ffn_b2[i - 87];
        else if (i < 111) { const int k = i - 93, c = k / 6, d = k - c * 6;
                            val = lnf_g[d] * head_w[c * 6 + d]; }
        else if (i < 114) { const int c = i - 111; float s = 0.0f;
                            #pragma unroll
                            for (int d = 0; d < 6; ++d) s += lnf_g[d] * head_w[c * 6 + d];
                            val = s; }
        else if (i < 117) { const int c = i - 114; float s = 0.0f;
                            #pragma unroll
                            for (int d = 0; d < 6; ++d) s += lnf_b[d] * head_w[c * 6 + d];
                            val = s; }
        else if (i >= 120 && i < 162) val = tok_emb[i - 120];
        wsm[i] = val;
    }

    // ---------------- stage idx tile as bytes: idsb[s][bl] ----------------
    // Global reads are exactly linear (idx[b0*34 + e]); LDS byte writes at
    // s*68+bl have 17-word stride across consecutive e -> conflict-free.
    {
        const int gb = b0 * TT;
        for (int e = tid; e < BCH * TT; e += BLK) {
            const int bl = e / TT, s = e - bl * TT;
            idsb[s * IDP + bl] = (unsigned char)idx[gb + e];
        }
        if (tid < BCH) idsb[TT * IDP + tid] = 0;   // prefetch-safety row
    }

    // ---------------- build (pos,tok) -> k,v table, rows [0, nrow) ----------------
    const float rs3l = 0.57735026918962576f * 1.4426950408889634f; // 1/sqrt(3)*log2e
    for (int e = tid; e < nrow * VV; e += BLK) {
        const int pos = e / VV, id = e - pos * VV;
        float x[6];
        x[0] = tok_emb[id * 3 + 0]; x[1] = tok_emb[id * 3 + 1]; x[2] = tok_emb[id * 3 + 2];
        x[3] = pos_enc[pos * 3 + 0]; x[4] = pos_enc[pos * 3 + 1]; x[5] = pos_enc[pos * 3 + 2];
        float mu = (x[0] + x[1] + x[2] + x[3] + x[4] + x[5]) * (1.0f / 6.0f);
        float var = 0.0f;
        #pragma unroll
        for (int d = 0; d < 6; ++d) { float dd = x[d] - mu; var += dd * dd; }
        const float rstd = rsqrtf(var * (1.0f / 6.0f) + 1e-5f);
        float h[6];
        #pragma unroll
        for (int d = 0; d < 6; ++d) h[d] = (x[d] - mu) * rstd * ln1_g[d] + ln1_b[d];
        float kk[6], vvv[6];
        #pragma unroll
        for (int r = 0; r < 6; ++r) {
            kk[r]  = (h[3] * k_w[r * 3 + 0] + h[4] * k_w[r * 3 + 1] + h[5] * k_w[r * 3 + 2]) * rs3l;
            vvv[r] =  h[0] * v_w[r * 3 + 0] + h[1] * v_w[r * 3 + 1] + h[2] * v_w[r * 3 + 2];
        }
        kvs[e * 3 + 0] = make_float4(kk[0], kk[1], kk[2], kk[3]);
        kvs[e * 3 + 1] = make_float4(kk[4], kk[5], vvv[0], vvv[1]);
        kvs[e * 3 + 2] = make_float4(vvv[2], vvv[3], vvv[4], vvv[5]);
    }
    __syncthreads();

    // ---------------- per-element work: wave w owns t = t_base + w ----------------
    const int w = tid >> 6, lane = tid & 63;
    const int t = t_base + w;
    const bool active = (t < TT);
    float lg[VV];

    if (active) {
        // own x (pre-LN residual): tok part from LDS, pos part wave-uniform from global
        const int myid = (int)idsb[t * IDP + lane];
        float x[6];
        x[0] = wsm[120 + myid * 3]; x[1] = wsm[121 + myid * 3]; x[2] = wsm[122 + myid * 3];
        x[3] = pos_enc[t * 3 + 0];  x[4] = pos_enc[t * 3 + 1];  x[5] = pos_enc[t * 3 + 2];

        // q (only h[3..5] needed)
        float q[6];
        {
            float mu = (x[0] + x[1] + x[2] + x[3] + x[4] + x[5]) * (1.0f / 6.0f);
            float var = 0.0f;
            #pragma unroll
            for (int d = 0; d < 6; ++d) { float dd = x[d] - mu; var += dd * dd; }
            const float rstd = rsqrtf(var * (1.0f / 6.0f) + 1e-5f);
            const float h3 = (x[3] - mu) * rstd * ln1_g[3] + ln1_b[3];
            const float h4 = (x[4] - mu) * rstd * ln1_g[4] + ln1_b[4];
            const float h5 = (x[5] - mu) * rstd * ln1_g[5] + ln1_b[5];
            #pragma unroll
            for (int r = 0; r < 6; ++r)
                q[r] = h3 * q_w[r * 3 + 0] + h4 * q_w[r * 3 + 1] + h5 * q_w[r * 3 + 2];
        }

        // causal attention, exp-sum softmax (scores bounded -> no max subtraction).
        // Uniform t per wave: exact trip count, no divergence. ids prefetched 1 ahead.
        float l0 = 0.f, l1 = 0.f;
        float a0 = 0.f, a1 = 0.f, a2 = 0.f, a3 = 0.f, a4 = 0.f, a5 = 0.f;
        const unsigned char* ip = idsb + lane;
        int ids = (int)ip[0];
        const float4* kp = kvs;
        for (int s = 0; s <= t; ++s) {
            const float4* e4 = kp + ids * 3;
            const float4 ka = e4[0];
            const float4 kb = e4[1];
            const float4 vb = e4[2];
            ids = (int)ip[(s + 1) * IDP];            // safe: padded row 34
            const float sc0 = q[0] * ka.x + q[1] * ka.y + q[2] * ka.z;
            const float sc1 = q[3] * ka.w + q[4] * kb.x + q[5] * kb.y;
            const float p0 = EXP2F(sc0);
            const float p1 = EXP2F(sc1);
            l0 += p0; l1 += p1;
            a0 += p0 * kb.z; a1 += p0 * kb.w; a2 += p0 * vb.x;
            a3 += p1 * vb.y; a4 += p1 * vb.z; a5 += p1 * vb.w;
            kp += VV * 3;
        }
        const float i0 = 1.0f / l0, i1 = 1.0f / l1;
        const float o6[6] = { a0 * i0, a1 * i0, a2 * i0, a3 * i1, a4 * i1, a5 * i1 };

        // residual + out proj
        #pragma unroll
        for (int d = 0; d < 6; ++d) {
            float s = x[d];
            #pragma unroll
            for (int j = 0; j < 6; ++j) s += o6[j] * wsm[d * 6 + j];
            x[d] = s;
        }

        // LN2 + FFN (exact gelu) + residual
        {
            float mu = (x[0] + x[1] + x[2] + x[3] + x[4] + x[5]) * (1.0f / 6.0f);
            float var = 0.0f;
            #pragma unroll
            for (int d = 0; d < 6; ++d) { float dd = x[d] - mu; var += dd * dd; }
            const float rstd = rsqrtf(var * (1.0f / 6.0f) + 1e-5f);
            float h2[6];
            #pragma unroll
            for (int d = 0; d < 6; ++d) h2[d] = (x[d] - mu) * rstd * wsm[36 + d] + wsm[42 + d];
            float g3[3];
            #pragma unroll
            for (int i = 0; i < 3; ++i) {
                float f = wsm[66 + i];
                #pragma unroll
                for (int d = 0; d < 6; ++d) f += h2[d] * wsm[48 + i * 6 + d];
                g3[i] = 0.5f * f * (1.0f + erff(f * 0.70710678118654752f));
            }
            #pragma unroll
            for (int d = 0; d < 6; ++d) {
                float s = x[d] + wsm[87 + d];
                #pragma unroll
                for (int i = 0; i < 3; ++i) s += g3[i] * wsm[69 + d * 3 + i];
                x[d] = s;
            }
        }

        // LNF folded into rank-3 head: y = rstd*(x.G_c - mu*sG_c) + eC_c; lg = y @ tok_emb^T
        {
            float mu = (x[0] + x[1] + x[2] + x[3] + x[4] + x[5]) * (1.0f / 6.0f);
            float var = 0.0f;
            #pragma unroll
            for (int d = 0; d < 6; ++d) { float dd = x[d] - mu; var += dd * dd; }
            const float rstd = rsqrtf(var * (1.0f / 6.0f) + 1e-5f);
            float y[3];
            #pragma unroll
            for (int c = 0; c < 3; ++c) {
                float dot = 0.0f;
                #pragma unroll
                for (int d = 0; d < 6; ++d) dot += x[d] * wsm[93 + c * 6 + d];
                y[c] = rstd * (dot - mu * wsm[111 + c]) + wsm[114 + c];
            }
            #pragma unroll
            for (int v = 0; v < VV; ++v)
                lg[v] = y[0] * wsm[120 + v * 3] + y[1] * wsm[121 + v * 3] + y[2] * wsm[122 + v * 3];
        }
    }
    __syncthreads();   // kvs readers done

    // ---------------- stage logits over kvs: lgs[bl][58] ----------------
    float* lgs = reinterpret_cast<float*>(kvs);
    if (active) {
        #pragma unroll
        for (int p = 0; p < 7; ++p)
            *reinterpret_cast<float2*>(&lgs[lane * 58 + w * 14 + 2 * p]) =
                make_float2(lg[2 * p], lg[2 * p + 1]);
    }
    __syncthreads();

    // ---------------- coalesced writeout: per b-row, nt*14 contiguous floats ----------------
    const int n7 = nt * BCH * 7;                 // float2 count
    const int sh = (tc == 8) ? 1 : 2;            // log2(nt)
    float* __restrict__ obase = out + (size_t)b0 * (TT * VV) + t_base * VV;
    for (int f = tid; f < n7; f += BLK) {
        const int q7 = f / 7, r7 = f - q7 * 7;
        const int bl2 = q7 >> sh, wsel = q7 & (nt - 1);
        const float2 v2 = *reinterpret_cast<const float2*>(&lgs[bl2 * 58 + wsel * 14 + 2 * r7]);
        *reinterpret_cast<float2*>(&obase[bl2 * (TT * VV) + wsel * VV + 2 * r7]) = v2;
    }
    (void)nst;
}

extern "C" void kernel_launch(void* const* d_in, const int* in_sizes, int n_in,
                              void* d_out, int out_size, void* d_ws, size_t ws_size,
                              hipStream_t stream) {
    const int*   idx     = (const int*)  d_in[0];
    const float* tok_emb = (const float*)d_in[1];
    const float* pos_enc = (const float*)d_in[2];
    const float* q_w     = (const float*)d_in[3];
    const float* k_w     = (const float*)d_in[4];
    const float* v_w     = (const float*)d_in[5];
    const float* out_w   = (const float*)d_in[6];
    const float* ln1_g   = (const float*)d_in[7];
    const float* ln1_b   = (const float*)d_in[8];
    const float* ln2_g   = (const float*)d_in[9];
    const float* ln2_b   = (const float*)d_in[10];
    const float* lnf_g   = (const float*)d_in[11];
    const float* lnf_b   = (const float*)d_in[12];
    const float* ffn_w1  = (const float*)d_in[13];
    const float* ffn_b1  = (const float*)d_in[14];
    const float* ffn_w2  = (const float*)d_in[15];
    const float* ffn_b2  = (const float*)d_in[16];
    const float* head_w  = (const float*)d_in[17];
    float* out = (float*)d_out;

    const int n  = in_sizes[0];         // B*T = 65536*34 = 2228224
    const int nb = n / TT;              // 65536 sequences
    const int blocks = (nb / BCH) * NCH; // 1024 b-chunks x 9 t-chunks = 9216
    addtx_fwd<<<blocks, BLK, 0, stream>>>(idx, tok_emb, pos_enc, q_w, k_w, v_w, out_w,
                                          ln1_g, ln1_b, ln2_g, ln2_b, lnf_g, lnf_b,
                                          ffn_w1, ffn_b1, ffn_w2, ffn_b2, head_w, out);
}

// Round 3
// 213.309 us; speedup vs baseline: 1.1547x; 1.1547x over previous
//
#include <hip/hip_runtime.h>
#include <math.h>

#define TT  34   // seq len
#define VV  14   // vocab
#define BLK 256  // threads per block

typedef float v2f __attribute__((ext_vector_type(2)));
typedef float v4f __attribute__((ext_vector_type(4)));

#if __has_builtin(__builtin_amdgcn_exp2f)
#define EXP2F(x) __builtin_amdgcn_exp2f(x)
#else
#define EXP2F(x) exp2f(x)
#endif
#if __has_builtin(__builtin_amdgcn_rcpf)
#define RCPF(x) __builtin_amdgcn_rcpf(x)
#else
#define RCPF(x) (1.0f/(x))
#endif

static __device__ __forceinline__ v2f fma2(v2f a, v2f b, v2f c) {
    return __builtin_elementwise_fma(a, b, c);   // -> v_pk_fma_f32 on gfx950
}
static __device__ __forceinline__ v2f bc2(float s) { v2f r; r.x = s; r.y = s; return r; }
#define SV2(v, a, b) __builtin_shufflevector((v), (v), (a), (b))

// wsm layout (floats), all v2f read-bases even (8B-aligned):
//   0..35   owT[j*6+d]   = out_w[d*6+j]
//  36..41   ln2_g        42..47 ln2_b
//  48..59   w1p[d*2+i]   = ffn_w1[i*6+d], i in {0,1}
//  60..65   w1r[d]       = ffn_w1[12+d]
//  66..68   ffn_b1       69 pad
//  70..87   w2T[i*6+d]   = ffn_w2[d*3+i]
//  88..93   ffn_b2       94..95 pad
//  96..107  Gp[d*2+c]    = lnf_g[d]*head_w[c*6+d], c in {0,1}
// 108..113  G2[d]        = lnf_g[d]*head_w[12+d]
// 114..117  pad
// 118..120  eC[c]        = sum_d lnf_b[d]*head_w[c*6+d]
// 121      pad
// 122..163  MT[c*14+v]   = tok_emb[v*3+c]   (fused head rows)
// 164..205  tok_emb natural [v*3+c]
// 206..307  pos_enc natural [t*3+c]

__global__ __launch_bounds__(BLK) void addtx_fwd(
    const int*   __restrict__ idx,
    const float* __restrict__ tok_emb,
    const float* __restrict__ pos_enc,
    const float* __restrict__ q_w,
    const float* __restrict__ k_w,
    const float* __restrict__ v_w,
    const float* __restrict__ out_w,
    const float* __restrict__ ln1_g, const float* __restrict__ ln1_b,
    const float* __restrict__ ln2_g, const float* __restrict__ ln2_b,
    const float* __restrict__ lnf_g, const float* __restrict__ lnf_b,
    const float* __restrict__ ffn_w1, const float* __restrict__ ffn_b1,
    const float* __restrict__ ffn_w2, const float* __restrict__ ffn_b2,
    const float* __restrict__ head_w,
    float* __restrict__ out)
{
    // kv entry e=(pos,tok), pair-interleaved for packed math, k pre-scaled 1/sqrt(3)*log2e:
    //  f4[0]=(k0,k3,k1,k4)  f4[1]=(k2,k5,v0,v3)  f4[2]=(v1,v4,v2,v5)
    // Reused as logits staging buffer after attention.
    __shared__ v4f   kvs[TT * VV * 3];   // 22848 B
    __shared__ float wsm[308];
    __shared__ int   idsb[308];          // this block's token ids * 48 (byte offsets)

    const int tid = threadIdx.x;
    const int blk = blockIdx.x;

    // ---------------- stage weights (transposed / pair-interleaved) ----------------
    for (int i = tid; i < 308; i += BLK) {
        float val = 0.0f;
        if (i < 36)       { const int j = i / 6, d = i - j * 6; val = out_w[d * 6 + j]; }
        else if (i < 42)  val = ln2_g[i - 36];
        else if (i < 48)  val = ln2_b[i - 42];
        else if (i < 60)  { const int k = i - 48, d = k >> 1, ii = k & 1; val = ffn_w1[ii * 6 + d]; }
        else if (i < 66)  val = ffn_w1[12 + (i - 60)];
        else if (i < 69)  val = ffn_b1[i - 66];
        else if (i < 70)  val = 0.0f;
        else if (i < 88)  { const int k = i - 70, ii = k / 6, d = k - ii * 6; val = ffn_w2[d * 3 + ii]; }
        else if (i < 94)  val = ffn_b2[i - 88];
        else if (i < 96)  val = 0.0f;
        else if (i < 108) { const int k = i - 96, d = k >> 1, c = k & 1; val = lnf_g[d] * head_w[c * 6 + d]; }
        else if (i < 114) { const int d = i - 108; val = lnf_g[d] * head_w[12 + d]; }
        else if (i < 118) val = 0.0f;
        else if (i < 121) { const int c = i - 118; float s = 0.0f;
                            #pragma unroll
                            for (int d = 0; d < 6; ++d) s += lnf_b[d] * head_w[c * 6 + d];
                            val = s; }
        else if (i < 122) val = 0.0f;
        else if (i < 164) { const int k = i - 122, c = k / 14, v = k - c * 14; val = tok_emb[v * 3 + c]; }
        else if (i < 206) val = tok_emb[i - 164];
        else              val = pos_enc[i - 206];
        wsm[i] = val;
    }

    // ---------------- stage this block's token ids (coalesced), pre-scaled *48 ----------------
    const int ntot = (int)gridDim.x * BLK;
    const int b0   = (blk * BLK) / TT;
    {
        const int gb = b0 * TT;
        for (int e = tid; e < 308; e += BLK) {
            const int g = gb + e;
            idsb[e] = (g < ntot) ? (idx[g] * 48) : 0;
        }
    }

    // ---------------- build (pos,tok) -> k,v table ----------------
    const float rs3l = 0.57735026918962576f * 1.4426950408889634f; // 1/sqrt(3)*log2e
    for (int e = tid; e < TT * VV; e += BLK) {
        const int pos = e / VV, id = e - pos * VV;
        float x[6];
        x[0] = tok_emb[id * 3 + 0]; x[1] = tok_emb[id * 3 + 1]; x[2] = tok_emb[id * 3 + 2];
        x[3] = pos_enc[pos * 3 + 0]; x[4] = pos_enc[pos * 3 + 1]; x[5] = pos_enc[pos * 3 + 2];
        float mu = (x[0] + x[1] + x[2] + x[3] + x[4] + x[5]) * (1.0f / 6.0f);
        float var = 0.0f;
        #pragma unroll
        for (int d = 0; d < 6; ++d) { float dd = x[d] - mu; var += dd * dd; }
        const float rstd = rsqrtf(var * (1.0f / 6.0f) + 1e-5f);
        float h[6];
        #pragma unroll
        for (int d = 0; d < 6; ++d) h[d] = (x[d] - mu) * rstd * ln1_g[d] + ln1_b[d];
        float kk[6], vvv[6];
        #pragma unroll
        for (int r = 0; r < 6; ++r) {
            kk[r]  = (h[3] * k_w[r * 3 + 0] + h[4] * k_w[r * 3 + 1] + h[5] * k_w[r * 3 + 2]) * rs3l;
            vvv[r] =  h[0] * v_w[r * 3 + 0] + h[1] * v_w[r * 3 + 1] + h[2] * v_w[r * 3 + 2];
        }
        v4f f0; f0.x = kk[0]; f0.y = kk[3]; f0.z = kk[1]; f0.w = kk[4];
        v4f f1; f1.x = kk[2]; f1.y = kk[5]; f1.z = vvv[0]; f1.w = vvv[3];
        v4f f2; f2.x = vvv[1]; f2.y = vvv[4]; f2.z = vvv[2]; f2.w = vvv[5];
        kvs[e * 3 + 0] = f0;
        kvs[e * 3 + 1] = f1;
        kvs[e * 3 + 2] = f2;
    }
    __syncthreads();

    // ---------------- t-balanced intra-block remap (closed form, verified r1) ----------------
    const int srank = (tid + ((blk & 3) << 6)) & (BLK - 1);
    const int r0 = (blk * BLK) % TT;
    const int m  = (TT - r0) % TT;
    int dsel, ksel;
    if (m < 18) {
        const int nA = (18 - m) << 3;
        if (srank < nA)            { dsel = m + (srank >> 3); ksel = srank & 7; }
        else if (srank < nA + 112) { const int r = srank - nA;       dsel = 18 + r / 7; ksel = r % 7; }
        else                       { const int r = srank - nA - 112; dsel = r >> 3;     ksel = r & 7; }
    } else {
        const int nA = (TT - m) * 7;
        if (srank < nA)            { dsel = m + srank / 7; ksel = srank % 7; }
        else if (srank < nA + 144) { const int r = srank - nA;       dsel = r >> 3;     ksel = r & 7; }
        else                       { const int r = srank - nA - 144; dsel = 18 + r / 7; ksel = r % 7; }
    }
    const int il   = dsel + ksel * TT;       // local slot in [0,256), bijection of tid
    const int flat = blk * BLK + il;
    const int b    = flat / TT;
    const int t    = flat - b * TT;
    const int* __restrict__ rowL = idsb + (b - b0) * TT;   // LDS-resident, values = id*48

    // ---------------- own x (pre-LN residual) and q ----------------
    float x[6];
    {
        const int tb = rowL[t] >> 4;   // id*3
        x[0] = wsm[164 + tb]; x[1] = wsm[165 + tb]; x[2] = wsm[166 + tb];
        x[3] = wsm[206 + t * 3]; x[4] = wsm[207 + t * 3]; x[5] = wsm[208 + t * 3];
    }
    float q[6];
    {
        float mu = (x[0] + x[1] + x[2] + x[3] + x[4] + x[5]) * (1.0f / 6.0f);
        float var = 0.0f;
        #pragma unroll
        for (int d = 0; d < 6; ++d) { float dd = x[d] - mu; var += dd * dd; }
        const float rstd = rsqrtf(var * (1.0f / 6.0f) + 1e-5f);
        const float h3 = (x[3] - mu) * rstd * ln1_g[3] + ln1_b[3];
        const float h4 = (x[4] - mu) * rstd * ln1_g[4] + ln1_b[4];
        const float h5 = (x[5] - mu) * rstd * ln1_g[5] + ln1_b[5];
        #pragma unroll
        for (int r = 0; r < 6; ++r)
            q[r] = h3 * q_w[r * 3 + 0] + h4 * q_w[r * 3 + 1] + h5 * q_w[r * 3 + 2];
    }
    const v2f Q03 = {q[0], q[3]}, Q14 = {q[1], q[4]}, Q25 = {q[2], q[5]};

    // ---------------- causal attention, packed 2-head exp-sum softmax ----------------
    // Scores bounded -> plain exp-sum == softmax in fp32. k carries the log2e scale.
    // ids prefetched one iteration ahead; all score/accum math is v_pk_fma_f32.
    v2f L = {0.f, 0.f}, A0 = {0.f, 0.f}, A1 = {0.f, 0.f}, A2 = {0.f, 0.f};
    int ids48 = rowL[0];
    const char* kp = (const char*)kvs;
    for (int s = 0; s <= t; ++s) {
        const v4f* e4 = (const v4f*)(kp + ids48);
        const v4f ka = e4[0], kb = e4[1], vb = e4[2];
        ids48 = rowL[s + 1];                     // safe: padded to 308
        v2f sc = fma2(Q03, SV2(ka, 0, 1),
                 fma2(Q14, SV2(ka, 2, 3),
                      Q25 * SV2(kb, 0, 1)));
        v2f p; p.x = EXP2F(sc.x); p.y = EXP2F(sc.y);
        L += p;
        A0 = fma2(p, SV2(kb, 2, 3), A0);
        A1 = fma2(p, SV2(vb, 0, 1), A1);
        A2 = fma2(p, SV2(vb, 2, 3), A2);
        kp += VV * 48;
    }
    v2f I; I.x = RCPF(L.x); I.y = RCPF(L.y);
    const v2f O0 = A0 * I, O1 = A1 * I, O2 = A2 * I;
    const float o6[6] = {O0.x, O1.x, O2.x, O0.y, O1.y, O2.y};

    // ---------------- residual + out proj (packed over d-pairs) ----------------
    v2f X0 = {x[0], x[1]}, X1 = {x[2], x[3]}, X2 = {x[4], x[5]};
    #define LD2(i) (*reinterpret_cast<const v2f*>(&wsm[(i)]))
    #pragma unroll
    for (int j = 0; j < 6; ++j) {
        const v2f oj = bc2(o6[j]);
        X0 = fma2(oj, LD2(j * 6 + 0), X0);
        X1 = fma2(oj, LD2(j * 6 + 2), X1);
        X2 = fma2(oj, LD2(j * 6 + 4), X2);
    }

    // ---------------- LN2 + FFN (exact gelu) + residual, packed ----------------
    {
        v2f S = X0 + X1 + X2;
        const float mu = (S.x + S.y) * (1.0f / 6.0f);
        const v2f muv = bc2(mu);
        const v2f D0 = X0 - muv, D1 = X1 - muv, D2 = X2 - muv;
        v2f E = fma2(D0, D0, fma2(D1, D1, D2 * D2));
        const float rstd = rsqrtf((E.x + E.y) * (1.0f / 6.0f) + 1e-5f);
        const v2f rs = bc2(rstd);
        const v2f H0 = fma2(D0 * rs, LD2(36), LD2(42));
        const v2f H1 = fma2(D1 * rs, LD2(38), LD2(44));
        const v2f H2 = fma2(D2 * rs, LD2(40), LD2(46));
        const float h[6] = {H0.x, H0.y, H1.x, H1.y, H2.x, H2.y};
        v2f F = LD2(66);
        float f2 = wsm[68];
        #pragma unroll
        for (int d = 0; d < 6; ++d) {
            F  = fma2(bc2(h[d]), LD2(48 + 2 * d), F);
            f2 = fmaf(h[d], wsm[60 + d], f2);
        }
        float g3[3];
        g3[0] = 0.5f * F.x * (1.0f + erff(F.x * 0.70710678118654752f));
        g3[1] = 0.5f * F.y * (1.0f + erff(F.y * 0.70710678118654752f));
        g3[2] = 0.5f * f2  * (1.0f + erff(f2  * 0.70710678118654752f));
        X0 += LD2(88); X1 += LD2(90); X2 += LD2(92);
        #pragma unroll
        for (int i = 0; i < 3; ++i) {
            const v2f gi = bc2(g3[i]);
            X0 = fma2(gi, LD2(70 + i * 6 + 0), X0);
            X1 = fma2(gi, LD2(70 + i * 6 + 2), X1);
            X2 = fma2(gi, LD2(70 + i * 6 + 4), X2);
        }
    }

    // ---------------- LNF folded into rank-3 head, packed ----------------
    v2f lgv[7];
    {
        v2f S = X0 + X1 + X2;
        const float mu = (S.x + S.y) * (1.0f / 6.0f);
        const v2f muv = bc2(mu);
        const v2f D0 = X0 - muv, D1 = X1 - muv, D2 = X2 - muv;
        v2f E = fma2(D0, D0, fma2(D1, D1, D2 * D2));
        const float rstd = rsqrtf((E.x + E.y) * (1.0f / 6.0f) + 1e-5f);
        const float xd[6] = {D0.x, D0.y, D1.x, D1.y, D2.x, D2.y};
        v2f D01 = {0.f, 0.f};
        float d2 = 0.f;
        #pragma unroll
        for (int d = 0; d < 6; ++d) {
            D01 = fma2(bc2(xd[d]), LD2(96 + 2 * d), D01);
            d2  = fmaf(xd[d], wsm[108 + d], d2);
        }
        const v2f y01 = fma2(bc2(rstd), D01, LD2(118));
        const float y2 = fmaf(rstd, d2, wsm[120]);
        const v2f Y0 = bc2(y01.x), Y1 = bc2(y01.y), Y2 = bc2(y2);
        #pragma unroll
        for (int mm = 0; mm < 7; ++mm)
            lgv[mm] = fma2(Y0, LD2(122 + 2 * mm),
                      fma2(Y1, LD2(136 + 2 * mm),
                           Y2 * LD2(150 + 2 * mm)));
    }
    __syncthreads();   // kvs readers done

    // ---------------- stage logits over kvs (dead) + coalesced writeout ----------------
    v2f* lg2 = reinterpret_cast<v2f*>(kvs);
    #pragma unroll
    for (int j = 0; j < 7; ++j)
        lg2[il * 7 + j] = lgv[j];
    __syncthreads();
    const v2f* s2 = reinterpret_cast<const v2f*>(kvs);
    v2f* __restrict__ ob2 = reinterpret_cast<v2f*>(out + (size_t)blk * (BLK * VV));
    #pragma unroll
    for (int j = 0; j < 7; ++j)
        ob2[j * BLK + tid] = s2[j * BLK + tid];
}

extern "C" void kernel_launch(void* const* d_in, const int* in_sizes, int n_in,
                              void* d_out, int out_size, void* d_ws, size_t ws_size,
                              hipStream_t stream) {
    const int*   idx     = (const int*)  d_in[0];
    const float* tok_emb = (const float*)d_in[1];
    const float* pos_enc = (const float*)d_in[2];
    const float* q_w     = (const float*)d_in[3];
    const float* k_w     = (const float*)d_in[4];
    const float* v_w     = (const float*)d_in[5];
    const float* out_w   = (const float*)d_in[6];
    const float* ln1_g   = (const float*)d_in[7];
    const float* ln1_b   = (const float*)d_in[8];
    const float* ln2_g   = (const float*)d_in[9];
    const float* ln2_b   = (const float*)d_in[10];
    const float* lnf_g   = (const float*)d_in[11];
    const float* lnf_b   = (const float*)d_in[12];
    const float* ffn_w1  = (const float*)d_in[13];
    const float* ffn_b1  = (const float*)d_in[14];
    const float* ffn_w2  = (const float*)d_in[15];
    const float* ffn_b2  = (const float*)d_in[16];
    const float* head_w  = (const float*)d_in[17];
    float* out = (float*)d_out;

    const int n = in_sizes[0];        // B*T = 65536*34 = 2228224, divisible by 256
    const int blocks = n / BLK;       // 8704
    addtx_fwd<<<blocks, BLK, 0, stream>>>(idx, tok_emb, pos_enc, q_w, k_w, v_w, out_w,
                                          ln1_g, ln1_b, ln2_g, ln2_b, lnf_g, lnf_b,
                                          ffn_w1, ffn_b1, ffn_w2, ffn_b2, head_w, out);
}